// Round 1
// baseline (340.969 us; speedup 1.0000x reference)
//
#include <hip/hip_runtime.h>
#include <hip/hip_bf16.h>
#include <cstdint>
#include <cstddef>

#define T_ 8
#define N_ 16384
#define D_ 512
#define H_ 1024
#define O_ 64
#define IDX_COUNT (T_*N_)   // 131072

typedef __attribute__((ext_vector_type(8))) short short8v;
typedef __attribute__((ext_vector_type(4))) float f32x4;

__device__ __forceinline__ short f2bf(float f) {
  unsigned u = __builtin_bit_cast(unsigned, f);
  u += 0x7fffu + ((u >> 16) & 1u);   // round-to-nearest-even
  return (short)(u >> 16);
}

// ---------------- indices kernel: indices == arange since node_type sorted ----------------
__global__ void idx_kernel(float* __restrict__ out) {
  int i = blockIdx.x * 256 + threadIdx.x;
  out[i] = (float)i;
}

// ---------------- weight conversion: f32 -> bf16, transposed + swizzled LDS tile images ----
// W1 tile per (t,hc,kk): [64 h][128 k] bf16 row-major (256B rows), byte ^= (h&7)<<4. 16384 B.
__global__ void prep_w1(const float* __restrict__ W1, char* __restrict__ ws) {
  int bid = blockIdx.x;            // t*64 + hc*4 + kk
  int kk = bid & 3, hc = (bid >> 2) & 15, t = bid >> 6;
  int tid = threadIdx.x;
  int h = tid & 63, ksub = tid >> 6;
  const float* src = W1 + ((size_t)(t*D_ + kk*128 + ksub*32))*H_ + hc*64 + h;
  short v[32];
#pragma unroll
  for (int i = 0; i < 32; i++) v[i] = f2bf(src[(size_t)i * H_]);  // coalesced: 64 lanes = 256B rows
  char* dst = ws + (size_t)bid * 16384;
#pragma unroll
  for (int g = 0; g < 4; g++) {
    int byt = (h*256 + (ksub*32 + g*8)*2) ^ ((h & 7) << 4);
    short8v p;
#pragma unroll
    for (int e = 0; e < 8; e++) p[e] = v[g*8 + e];
    *(short8v*)(dst + byt) = p;
  }
}

// W2 tile per (t,hc): [64 o][64 hh] bf16 row-major (128B rows), byte ^= (o&7)<<4. 8192 B.
__global__ void prep_w2(const float* __restrict__ W2, char* __restrict__ ws) {
  int bid = blockIdx.x;            // t*16 + hc
  int hc = bid & 15, t = bid >> 4;
  int tid = threadIdx.x;
  int o = tid & 63, hsub = tid >> 6;
  const float* src = W2 + ((size_t)(t*H_ + hc*64 + hsub*16))*O_ + o;
  short v[16];
#pragma unroll
  for (int i = 0; i < 16; i++) v[i] = f2bf(src[(size_t)i * O_]);
  char* dst = ws + (size_t)bid * 8192;
#pragma unroll
  for (int g = 0; g < 2; g++) {
    int byt = (o*128 + (hsub*16 + g*8)*2) ^ ((o & 7) << 4);
    short8v p;
#pragma unroll
    for (int e = 0; e < 8; e++) p[e] = v[g*8 + e];
    *(short8v*)(dst + byt) = p;
  }
}

// ---------------- fused GEMM1 -> sigmoid -> GEMM2 ----------------
__device__ __forceinline__ void gl_lds16(const void* g, void* l) {
  __builtin_amdgcn_global_load_lds((const __attribute__((address_space(1))) unsigned int*)g,
                                   (__attribute__((address_space(3))) unsigned int*)l, 16, 0, 0);
}

__global__ __launch_bounds__(512) void gemm_fused(
    const float* __restrict__ x, const float* __restrict__ b1,
    const float* __restrict__ b2, const char* __restrict__ wsw1,
    const char* __restrict__ wsw2, float* __restrict__ out)
{
  __shared__ __align__(16) char  w1buf[2][16384];
  __shared__ __align__(16) char  w2buf[8192];
  __shared__ __align__(16) short lds_h[128*72];     // row stride 72 elem = 144B (16B-mult, 2-way banks)

  const int tid = threadIdx.x;
  const int lane = tid & 63;
  const int w = tid >> 6;                 // wave 0..7
  // XCD swizzle: 1024 blocks, 8 XCDs -> one type per XCD (shares W1_t in L2)
  const int bid = ((blockIdx.x & 7) << 7) | (blockIdx.x >> 3);
  const int t = bid >> 7;                 // 128 blocks per type
  const int rblk = bid & 127;
  const int lrow = lane & 15;             // fragment row/col id
  const int lk = lane >> 4;               // k-group 0..3

  // ---- phase 0: x rows -> persistent A fragments (bf16), read exactly once, coalesced ----
  short8v afrag[16];
  {
    const float* xr = x + ((size_t)(t*N_ + rblk*128 + w*16 + lrow))*D_ + lk*8;
#pragma unroll
    for (int ks = 0; ks < 16; ks++) {
      const f32x4* p = (const f32x4*)(xr + ks*32);
      f32x4 v0 = p[0], v1 = p[1];
      short8v a;
      a[0]=f2bf(v0[0]); a[1]=f2bf(v0[1]); a[2]=f2bf(v0[2]); a[3]=f2bf(v0[3]);
      a[4]=f2bf(v1[0]); a[5]=f2bf(v1[1]); a[6]=f2bf(v1[2]); a[7]=f2bf(v1[3]);
      afrag[ks] = a;
    }
  }

  f32x4 oacc[4];
#pragma unroll
  for (int i = 0; i < 4; i++) oacc[i] = (f32x4){0.f,0.f,0.f,0.f};

  const char* w1base = wsw1 + ((size_t)t*64)*16384;
  const char* w2base = wsw2 + ((size_t)t*16)*8192;

  // prologue: stage W1 tile 0 and W2 chunk 0
  gl_lds16(w1base + tid*16,        &w1buf[0][w*1024]);
  gl_lds16(w1base + 8192 + tid*16, &w1buf[0][8192 + w*1024]);
  gl_lds16(w2base + tid*16,        &w2buf[w*1024]);
  __syncthreads();

  for (int hc = 0; hc < 16; hc++) {
    f32x4 hacc[4];
#pragma unroll
    for (int i = 0; i < 4; i++) hacc[i] = (f32x4){0.f,0.f,0.f,0.f};
    float bias1[4];
#pragma unroll
    for (int cf = 0; cf < 4; cf++) bias1[cf] = b1[t*H_ + hc*64 + cf*16 + lrow];

#pragma unroll
    for (int kk = 0; kk < 4; kk++) {
      const int tt = hc*4 + kk;
      if (tt + 1 < 64) {   // prefetch next W1 tile into the other buffer
        const char* g = w1base + (size_t)(tt+1)*16384;
        char* l = w1buf[(tt+1) & 1];
        gl_lds16(g + tid*16,        l + w*1024);
        gl_lds16(g + 8192 + tid*16, l + 8192 + w*1024);
      }
      const char* buf = w1buf[tt & 1];
#pragma unroll
      for (int ks = 0; ks < 4; ks++) {
#pragma unroll
        for (int cf = 0; cf < 4; cf++) {
          const int h = cf*16 + lrow;
          const int byt = (h*256 + (ks*32 + lk*8)*2) ^ ((h & 7) << 4);
          short8v bfr = *(const short8v*)(buf + byt);
          hacc[cf] = __builtin_amdgcn_mfma_f32_16x16x32_bf16(afrag[kk*4+ks], bfr, hacc[cf], 0, 0, 0);
        }
      }
      __syncthreads();   // drains vmcnt (prefetch complete) + protects buffer reuse
    }

    // bias + sigmoid + redistribute D-frag -> A-frag through wave-local LDS slice
#pragma unroll
    for (int cf = 0; cf < 4; cf++) {
#pragma unroll
      for (int j = 0; j < 4; j++) {
        float v = hacc[cf][j] + bias1[cf];
        float s = 1.f / (1.f + __expf(-v));
        lds_h[(w*16 + lk*4 + j)*72 + cf*16 + lrow] = f2bf(s);
      }
    }
    // GEMM2: out_tile += h_chunk @ W2_chunk (wave-local lds_h rows; DS pipe is in-order per wave)
#pragma unroll
    for (int ks2 = 0; ks2 < 2; ks2++) {
      short8v ha = *(const short8v*)(&lds_h[(w*16 + lrow)*72 + ks2*32 + lk*8]);
#pragma unroll
      for (int cf = 0; cf < 4; cf++) {
        const int o = cf*16 + lrow;
        const int byt = (o*128 + (ks2*32 + lk*8)*2) ^ ((o & 7) << 4);
        short8v bfr = *(const short8v*)(w2buf + byt);
        oacc[cf] = __builtin_amdgcn_mfma_f32_16x16x32_bf16(ha, bfr, oacc[cf], 0, 0, 0);
      }
    }
    __syncthreads();   // all waves done reading w2buf before restage
    if (hc + 1 < 16) gl_lds16(w2base + (size_t)(hc+1)*8192 + tid*16, &w2buf[w*1024]);
  }

  // epilogue
  float bias2[4];
#pragma unroll
  for (int cf = 0; cf < 4; cf++) bias2[cf] = b2[t*O_ + cf*16 + lrow];
  float* ob = out + IDX_COUNT + ((size_t)(t*N_ + rblk*128 + w*16 + lk*4))*O_;
#pragma unroll
  for (int cf = 0; cf < 4; cf++)
#pragma unroll
    for (int j = 0; j < 4; j++)
      ob[(size_t)j*O_ + cf*16 + lrow] = oacc[cf][j] + bias2[cf];
}

// ---------------- naive f32 fallback (only if ws too small) ----------------
__global__ void naive_kernel(const float* __restrict__ x, const float* __restrict__ W1,
                             const float* __restrict__ b1, const float* __restrict__ W2,
                             const float* __restrict__ b2, float* __restrict__ out) {
  const int row = blockIdx.x;             // 0..131071
  const int t = row >> 14;
  __shared__ float xs[512];
  __shared__ float hs[1024];
  const float* xr = x + (size_t)row * D_;
  for (int i = threadIdx.x; i < D_; i += 256) xs[i] = xr[i];
  __syncthreads();
  const float* w1t = W1 + (size_t)t * D_ * H_;
  for (int h = threadIdx.x; h < H_; h += 256) {
    float acc = b1[t*H_ + h];
    for (int k = 0; k < D_; k++) acc += xs[k] * w1t[(size_t)k*H_ + h];
    hs[h] = 1.f / (1.f + __expf(-acc));
  }
  __syncthreads();
  const float* w2t = W2 + (size_t)t * H_ * O_;
  for (int o = threadIdx.x; o < O_; o += 256) {
    float acc = b2[t*O_ + o];
    for (int k = 0; k < H_; k++) acc += hs[k] * w2t[k*O_ + o];
    out[IDX_COUNT + (size_t)row*O_ + o] = acc;
  }
}

extern "C" void kernel_launch(void* const* d_in, const int* in_sizes, int n_in,
                              void* d_out, int out_size, void* d_ws, size_t ws_size,
                              hipStream_t stream) {
  const float* x  = (const float*)d_in[0];
  const float* W1 = (const float*)d_in[1];
  const float* b1 = (const float*)d_in[2];
  const float* W2 = (const float*)d_in[3];
  const float* b2 = (const float*)d_in[4];
  float* out = (float*)d_out;

  idx_kernel<<<IDX_COUNT/256, 256, 0, stream>>>(out);

  const size_t w1_bytes = (size_t)T_*64*16384;   // 8,388,608
  const size_t w2_bytes = (size_t)T_*16*8192;    // 1,048,576
  if (ws_size >= w1_bytes + w2_bytes) {
    char* wsw1 = (char*)d_ws;
    char* wsw2 = wsw1 + w1_bytes;
    prep_w1<<<T_*64, 256, 0, stream>>>(W1, wsw1);
    prep_w2<<<T_*16, 256, 0, stream>>>(W2, wsw2);
    gemm_fused<<<T_*(N_/128), 512, 0, stream>>>(x, b1, b2, wsw1, wsw2, out);
  } else {
    naive_kernel<<<T_*N_, 256, 0, stream>>>(x, W1, b1, W2, b2, out);
  }
}

// Round 3
// 279.437 us; speedup vs baseline: 1.2202x; 1.2202x over previous
//
#include <hip/hip_runtime.h>
#include <hip/hip_bf16.h>
#include <cstdint>
#include <cstddef>

#define T_ 8
#define N_ 16384
#define D_ 512
#define H_ 1024
#define O_ 64
#define IDX_COUNT (T_*N_)   // 131072

typedef __attribute__((ext_vector_type(8))) short short8v;
typedef __attribute__((ext_vector_type(4))) float f32x4;

__device__ __forceinline__ short f2bf(float f) {
  unsigned u = __builtin_bit_cast(unsigned, f);
  u += 0x7fffu + ((u >> 16) & 1u);   // round-to-nearest-even
  return (short)(u >> 16);
}

// ---------------- indices kernel: node_type is sorted repeat(arange(T)) -> indices == arange
__global__ void idx_kernel(float* __restrict__ out) {
  int i = blockIdx.x * 256 + threadIdx.x;
  out[i] = (float)i;
}

// ---------------- prep_w1: W1 f32 -> bf16 lane-linear A-fragment tiles (register-only) ----
// Tile (t,hc,kk) = 16KB: chunk ch = ks*256 + hf*64 + lane; lane = g*16 + r
//   chunk elem e = W1[t][d = kk*128 + ks*32 + g*8 + e][h = hc*64 + hf*16 + r]
__global__ void prep_w1(const float* __restrict__ W1, char* __restrict__ ws) {
  int bid = blockIdx.x;            // t*64 + hc*4 + kk
  int kk = bid & 3, hc = (bid >> 2) & 15, t = bid >> 6;
  int tid = threadIdx.x;
  char* dst = ws + (size_t)bid * 16384;
  const float* src = W1 + ((size_t)t*D_ + kk*128)*H_ + hc*64;
#pragma unroll
  for (int i = 0; i < 4; i++) {
    int ch = i*256 + tid;          // 1024 16B chunks
    int lane = ch & 63, hf = (ch >> 6) & 3, ks = ch >> 8;
    int r = lane & 15, g = lane >> 4;
    short8v p;
#pragma unroll
    for (int e = 0; e < 8; e++)
      p[e] = f2bf(src[(size_t)(ks*32 + g*8 + e)*H_ + hf*16 + r]);
    *(short8v*)(dst + ch*16) = p;
  }
}

// ---------------- prep_w2: W2 f32 -> bf16 A-frags, k scrambled to match in-lane H pack ----
// Chunk (t,hc) = 8KB: ch = kb*256 + of*64 + lane; elem e = m*4+j
//   value = W2[t][h = hc*64 + kb*32 + m*16 + g*4 + j][o = of*16 + r]
__global__ void prep_w2(const float* __restrict__ W2, char* __restrict__ ws) {
  int bid = blockIdx.x;            // t*16 + hc
  int hc = bid & 15, t = bid >> 4;
  int tid = threadIdx.x;
  char* dst = ws + (size_t)bid * 8192;
  const float* src = W2 + ((size_t)t*H_ + hc*64)*O_;
#pragma unroll
  for (int i = 0; i < 2; i++) {
    int ch = i*256 + tid;          // 512 16B chunks
    int lane = ch & 63, of = (ch >> 6) & 3, kb = ch >> 8;
    int r = lane & 15, g = lane >> 4;
    short8v p;
#pragma unroll
    for (int e = 0; e < 8; e++) {
      int m = e >> 2, j = e & 3;
      p[e] = f2bf(src[(size_t)(kb*32 + m*16 + g*4 + j)*O_ + of*16 + r]);
    }
    *(short8v*)(dst + ch*16) = p;
  }
}

// ---------------- fused GEMM1 -> sigmoid -> GEMM2 (swapped operands) ----------------
__device__ __forceinline__ void gl_lds16(const void* g, void* l) {
  __builtin_amdgcn_global_load_lds((const __attribute__((address_space(1))) unsigned int*)g,
                                   (__attribute__((address_space(3))) unsigned int*)l, 16, 0, 0);
}

__global__ __launch_bounds__(512, 2) void gemm_fused(
    const float* __restrict__ x, const float* __restrict__ b1,
    const float* __restrict__ b2, const char* __restrict__ wsw1,
    const char* __restrict__ wsw2, float* __restrict__ out)
{
  __shared__ __align__(16) char w1buf[2][16384];   // W1 tile double buffer
  __shared__ __align__(16) char w2buf[2][8192];    // W2 chunk double buffer

  const int tid = threadIdx.x;
  const int lane = tid & 63;
  const int w = tid >> 6;                  // wave 0..7, owns 32 rows
  // XCD swizzle: 512 blocks -> one type per XCD (W1_t 1MB stays L2-resident)
  const int bid = ((blockIdx.x & 7) << 6) | (blockIdx.x >> 3);
  const int t = bid >> 6;
  const int rblk = bid & 63;               // 64 row-blocks of 256 rows per type
  const int r = lane & 15;
  const int g = lane >> 4;

  const char* w1base = wsw1 + (size_t)t * (64*16384);
  const char* w2base = wsw2 + (size_t)t * (16*8192);

  // prologue: stage W1 tile 0 + W2 chunk 0 (R1-proven pattern: 512thr, 2x8KB strides)
  gl_lds16(w1base + tid*16,        &w1buf[0][w*1024]);
  gl_lds16(w1base + 8192 + tid*16, &w1buf[0][8192 + w*1024]);
  gl_lds16(w2base + tid*16,        &w2buf[0][w*1024]);

  // x rows -> persistent B-fragments (bf16), read exactly once, coalesced.
  // xf[nf][ki]: lane holds x[n = rblk*256 + w*32 + nf*16 + r][d = ki*32 + g*8 + e]
  short8v xf[2][16];
#pragma unroll
  for (int nf = 0; nf < 2; nf++) {
    const float* xr = x + ((size_t)(t*N_ + rblk*256 + w*32 + nf*16 + r))*D_ + g*8;
#pragma unroll
    for (int ki = 0; ki < 16; ki++) {
      const f32x4* p = (const f32x4*)(xr + ki*32);
      f32x4 v0 = p[0], v1 = p[1];
      short8v a;
      a[0]=f2bf(v0[0]); a[1]=f2bf(v0[1]); a[2]=f2bf(v0[2]); a[3]=f2bf(v0[3]);
      a[4]=f2bf(v1[0]); a[5]=f2bf(v1[1]); a[6]=f2bf(v1[2]); a[7]=f2bf(v1[3]);
      xf[nf][ki] = a;
    }
  }

  f32x4 oacc[4][2];   // O^T frags [of][nf]: lane o = of*16+g*4+j, n = nf*16+r
#pragma unroll
  for (int i = 0; i < 4; i++)
#pragma unroll
    for (int nf = 0; nf < 2; nf++) oacc[i][nf] = (f32x4){0.f,0.f,0.f,0.f};

  __syncthreads();   // prologue staging drained

  for (int hc = 0; hc < 16; hc++) {
    f32x4 hacc[4][2];  // H^T frags [hf][nf]: lane h = hf*16+g*4+j, n = nf*16+r
#pragma unroll
    for (int i = 0; i < 4; i++)
#pragma unroll
      for (int nf = 0; nf < 2; nf++) hacc[i][nf] = (f32x4){0.f,0.f,0.f,0.f};

#pragma unroll
    for (int kk = 0; kk < 4; kk++) {
      const int tt = hc*4 + kk;
      if (tt < 63) {                          // prefetch next W1 tile (other parity buffer)
        const char* gsrc = w1base + (size_t)(tt+1)*16384;
        char* nb = &w1buf[(kk+1)&1][0];
        gl_lds16(gsrc + tid*16,        nb + w*1024);
        gl_lds16(gsrc + 8192 + tid*16, nb + 8192 + w*1024);
      }
      if (kk == 1 && hc < 15) {               // W2 prefetch: after kk0-barrier, so GEMM2(hc-1)
        char* nb = &w2buf[(hc+1)&1][0];       // readers of this buffer are provably done
        gl_lds16(w2base + (size_t)(hc+1)*8192 + tid*16, nb + w*1024);
      }
      const char* curw1 = &w1buf[kk&1][0];
#pragma unroll
      for (int ks = 0; ks < 4; ks++)
#pragma unroll
        for (int hf = 0; hf < 4; hf++) {
          // lane-linear conflict-free 16B fragment read
          short8v wf = *(const short8v*)(curw1 + (((ks*4 + hf)*64 + lane) << 4));
          hacc[hf][0] = __builtin_amdgcn_mfma_f32_16x16x32_bf16(wf, xf[0][kk*4+ks], hacc[hf][0], 0,0,0);
          hacc[hf][1] = __builtin_amdgcn_mfma_f32_16x16x32_bf16(wf, xf[1][kk*4+ks], hacc[hf][1], 0,0,0);
        }
      __syncthreads();   // next tile staged + this tile's readers done
    }

    // bias + sigmoid + in-lane bf16 pack: H^T D-frag -> GEMM2 B-frag (no LDS round trip)
    const float* b1p = b1 + t*H_ + hc*64;
    short8v hb[2][2];   // [kb][nf]; elem e=m*4+j holds h = kb*32 + m*16 + g*4 + j
#pragma unroll
    for (int hf = 0; hf < 4; hf++) {
      const int kb = hf >> 1, m = hf & 1;
      f32x4 bv = *(const f32x4*)(b1p + hf*16 + g*4);
#pragma unroll
      for (int nf = 0; nf < 2; nf++)
#pragma unroll
        for (int j = 0; j < 4; j++) {
          float v = hacc[hf][nf][j] + bv[j];
          float s = 1.f / (1.f + __expf(-v));
          hb[kb][nf][m*4 + j] = f2bf(s);
        }
    }

    // GEMM2: O^T += W2^T(scrambled-k) . H^T  (k-permutation cancels between operands)
    const char* curw2 = (hc & 1) ? &w2buf[1][0] : &w2buf[0][0];
#pragma unroll
    for (int kb = 0; kb < 2; kb++)
#pragma unroll
      for (int of = 0; of < 4; of++) {
        short8v wf = *(const short8v*)(curw2 + (((kb*4 + of)*64 + lane) << 4));
        oacc[of][0] = __builtin_amdgcn_mfma_f32_16x16x32_bf16(wf, hb[kb][0], oacc[of][0], 0,0,0);
        oacc[of][1] = __builtin_amdgcn_mfma_f32_16x16x32_bf16(wf, hb[kb][1], oacc[of][1], 0,0,0);
      }
  }

  // epilogue: direct f32x4 stores, no LDS. Lane (r,g) owns 4 consecutive floats per row;
  // 4 lanes (g=0..3) fill each 64B line -> line-granular coalescing.
  const float* b2p = b2 + t*O_;
  float* obase = out + IDX_COUNT + ((size_t)(t*N_ + rblk*256 + w*32))*O_;
#pragma unroll
  for (int nf = 0; nf < 2; nf++)
#pragma unroll
    for (int of = 0; of < 4; of++) {
      f32x4 bv = *(const f32x4*)(b2p + of*16 + g*4);
      f32x4 v;
#pragma unroll
      for (int j = 0; j < 4; j++) v[j] = oacc[of][nf][j] + bv[j];
      *(f32x4*)(obase + (size_t)(nf*16 + r)*O_ + of*16 + g*4) = v;
    }
}

// ---------------- naive f32 fallback (only if ws too small) ----------------
__global__ void naive_kernel(const float* __restrict__ x, const float* __restrict__ W1,
                             const float* __restrict__ b1, const float* __restrict__ W2,
                             const float* __restrict__ b2, float* __restrict__ out) {
  const int row = blockIdx.x;
  const int t = row >> 14;
  __shared__ float xs[512];
  __shared__ float hs[1024];
  const float* xr = x + (size_t)row * D_;
  for (int i = threadIdx.x; i < D_; i += 256) xs[i] = xr[i];
  __syncthreads();
  const float* w1t = W1 + (size_t)t * D_ * H_;
  for (int h = threadIdx.x; h < H_; h += 256) {
    float acc = b1[t*H_ + h];
    for (int k = 0; k < D_; k++) acc += xs[k] * w1t[(size_t)k*H_ + h];
    hs[h] = 1.f / (1.f + __expf(-acc));
  }
  __syncthreads();
  const float* w2t = W2 + (size_t)t * H_ * O_;
  for (int o = threadIdx.x; o < O_; o += 256) {
    float acc = b2[t*O_ + o];
    for (int k = 0; k < H_; k++) acc += hs[k] * w2t[k*O_ + o];
    out[IDX_COUNT + (size_t)row*O_ + o] = acc;
  }
}

extern "C" void kernel_launch(void* const* d_in, const int* in_sizes, int n_in,
                              void* d_out, int out_size, void* d_ws, size_t ws_size,
                              hipStream_t stream) {
  const float* x  = (const float*)d_in[0];
  const float* W1 = (const float*)d_in[1];
  const float* b1 = (const float*)d_in[2];
  const float* W2 = (const float*)d_in[3];
  const float* b2 = (const float*)d_in[4];
  float* out = (float*)d_out;

  idx_kernel<<<IDX_COUNT/256, 256, 0, stream>>>(out);

  const size_t w1_bytes = (size_t)T_*64*16384;   // 8,388,608
  const size_t w2_bytes = (size_t)T_*16*8192;    // 1,048,576
  if (ws_size >= w1_bytes + w2_bytes) {
    char* wsw1 = (char*)d_ws;
    char* wsw2 = wsw1 + w1_bytes;
    prep_w1<<<T_*64, 256, 0, stream>>>(W1, wsw1);
    prep_w2<<<T_*16, 256, 0, stream>>>(W2, wsw2);
    gemm_fused<<<T_*(N_/256), 512, 0, stream>>>(x, b1, b2, wsw1, wsw2, out);
  } else {
    naive_kernel<<<T_*N_, 256, 0, stream>>>(x, W1, b1, W2, b2, out);
  }
}

// Round 4
// 249.375 us; speedup vs baseline: 1.3673x; 1.1206x over previous
//
#include <hip/hip_runtime.h>
#include <hip/hip_bf16.h>
#include <cstdint>
#include <cstddef>

#define T_ 8
#define N_ 16384
#define D_ 512
#define H_ 1024
#define O_ 64
#define IDX_COUNT (T_*N_)   // 131072

typedef __attribute__((ext_vector_type(8))) short short8v;
typedef __attribute__((ext_vector_type(4))) float f32x4;

__device__ __forceinline__ short f2bf(float f) {
  unsigned u = __builtin_bit_cast(unsigned, f);
  u += 0x7fffu + ((u >> 16) & 1u);   // round-to-nearest-even
  return (short)(u >> 16);
}

// ---------------- indices kernel: node_type is sorted repeat(arange(T)) -> indices == arange
__global__ void idx_kernel(float* __restrict__ out) {
  int i = blockIdx.x * 256 + threadIdx.x;
  out[i] = (float)i;
}

// ---------------- prep_w1: W1 f32 -> bf16 lane-linear A-fragment tiles (register-only) ----
// Tile (t,hc,kk) = 16KB: chunk ch = ks*256 + hf*64 + lane; lane = g*16 + r
//   chunk elem e = W1[t][d = kk*128 + ks*32 + g*8 + e][h = hc*64 + hf*16 + r]
__global__ void prep_w1(const float* __restrict__ W1, char* __restrict__ ws) {
  int bid = blockIdx.x;            // t*64 + hc*4 + kk
  int kk = bid & 3, hc = (bid >> 2) & 15, t = bid >> 6;
  int tid = threadIdx.x;
  char* dst = ws + (size_t)bid * 16384;
  const float* src = W1 + ((size_t)t*D_ + kk*128)*H_ + hc*64;
#pragma unroll
  for (int i = 0; i < 4; i++) {
    int ch = i*256 + tid;          // 1024 16B chunks
    int lane = ch & 63, hf = (ch >> 6) & 3, ks = ch >> 8;
    int r = lane & 15, g = lane >> 4;
    short8v p;
#pragma unroll
    for (int e = 0; e < 8; e++)
      p[e] = f2bf(src[(size_t)(ks*32 + g*8 + e)*H_ + hf*16 + r]);
    *(short8v*)(dst + ch*16) = p;
  }
}

// ---------------- prep_w2: W2 f32 -> bf16 A-frags, k scrambled to match in-lane H pack ----
// Chunk (t,hc) = 8KB: ch = kb*256 + of*64 + lane; elem e = m*4+j
//   value = W2[t][h = hc*64 + kb*32 + m*16 + g*4 + j][o = of*16 + r]
__global__ void prep_w2(const float* __restrict__ W2, char* __restrict__ ws) {
  int bid = blockIdx.x;            // t*16 + hc
  int hc = bid & 15, t = bid >> 4;
  int tid = threadIdx.x;
  char* dst = ws + (size_t)bid * 8192;
  const float* src = W2 + ((size_t)t*H_ + hc*64)*O_;
#pragma unroll
  for (int i = 0; i < 2; i++) {
    int ch = i*256 + tid;          // 512 16B chunks
    int lane = ch & 63, of = (ch >> 6) & 3, kb = ch >> 8;
    int r = lane & 15, g = lane >> 4;
    short8v p;
#pragma unroll
    for (int e = 0; e < 8; e++) {
      int m = e >> 2, j = e & 3;
      p[e] = f2bf(src[(size_t)(kb*32 + m*16 + g*4 + j)*O_ + of*16 + r]);
    }
    *(short8v*)(dst + ch*16) = p;
  }
}

// ---------------- fused GEMM1 -> sigmoid -> GEMM2 (swapped operands) ----------------
__device__ __forceinline__ void gl_lds16(const void* g, void* l) {
  __builtin_amdgcn_global_load_lds((const __attribute__((address_space(1))) unsigned int*)g,
                                   (__attribute__((address_space(3))) unsigned int*)l, 16, 0, 0);
}

// 256 threads / 4 waves / 128 rows per block. min 2 waves/EU -> 256 VGPR cap:
// xf(128) + hacc(32) + oacc(32) + hb(16) + temps fits WITHOUT spilling (R3 spilled at 128).
__global__ __launch_bounds__(256, 2) void gemm_fused(
    const float* __restrict__ x, const float* __restrict__ b1,
    const float* __restrict__ b2, const char* __restrict__ wsw1,
    const char* __restrict__ wsw2, float* __restrict__ out)
{
  __shared__ __align__(16) char w1buf[2][16384];   // W1 tile double buffer
  __shared__ __align__(16) char w2buf[2][8192];    // W2 chunk double buffer

  const int tid = threadIdx.x;
  const int lane = tid & 63;
  const int w = tid >> 6;                  // wave 0..3, owns 32 rows
  // XCD swizzle: 1024 blocks -> one type per XCD (W1_t 1MB stays L2-resident)
  const int bid = ((blockIdx.x & 7) << 7) | (blockIdx.x >> 3);
  const int t = bid >> 7;
  const int rblk = bid & 127;              // 128 row-blocks of 128 rows per type
  const int r = lane & 15;
  const int g = lane >> 4;

  const char* w1base = wsw1 + (size_t)t * (64*16384);
  const char* w2base = wsw2 + (size_t)t * (16*8192);

  // prologue: stage W1 tile 0 + W2 chunk 0 (issued first; they fly under the x loads)
#pragma unroll
  for (int s = 0; s < 4; s++)
    gl_lds16(w1base + s*4096 + tid*16, &w1buf[0][s*4096 + w*1024]);
#pragma unroll
  for (int s = 0; s < 2; s++)
    gl_lds16(w2base + s*4096 + tid*16, &w2buf[0][s*4096 + w*1024]);

  // x rows -> persistent B-fragments (bf16), read exactly once, coalesced.
  // xf[nf][ki]: lane holds x[n = rblk*128 + w*32 + nf*16 + r][d = ki*32 + g*8 + e]
  short8v xf[2][16];
#pragma unroll
  for (int nf = 0; nf < 2; nf++) {
    const float* xr = x + ((size_t)(t*N_ + rblk*128 + w*32 + nf*16 + r))*D_ + g*8;
#pragma unroll
    for (int ki = 0; ki < 16; ki++) {
      const f32x4* p = (const f32x4*)(xr + ki*32);
      f32x4 v0 = p[0], v1 = p[1];
      short8v a;
      a[0]=f2bf(v0[0]); a[1]=f2bf(v0[1]); a[2]=f2bf(v0[2]); a[3]=f2bf(v0[3]);
      a[4]=f2bf(v1[0]); a[5]=f2bf(v1[1]); a[6]=f2bf(v1[2]); a[7]=f2bf(v1[3]);
      xf[nf][ki] = a;
    }
  }

  f32x4 oacc[4][2];   // O^T frags [of][nf]: lane o = of*16+g*4+j, n = nf*16+r
#pragma unroll
  for (int i = 0; i < 4; i++)
#pragma unroll
    for (int nf = 0; nf < 2; nf++) oacc[i][nf] = (f32x4){0.f,0.f,0.f,0.f};

  __syncthreads();   // prologue staging drained

  for (int hc = 0; hc < 16; hc++) {
    f32x4 hacc[4][2];  // H^T frags [hf][nf]: lane h = hf*16+g*4+j, n = nf*16+r
#pragma unroll
    for (int i = 0; i < 4; i++)
#pragma unroll
      for (int nf = 0; nf < 2; nf++) hacc[i][nf] = (f32x4){0.f,0.f,0.f,0.f};

#pragma unroll
    for (int kk = 0; kk < 4; kk++) {
      const int tt = hc*4 + kk;
      if (tt < 63) {                          // prefetch next W1 tile (other parity buffer)
        const char* gsrc = w1base + (size_t)(tt+1)*16384;
        char* nb = &w1buf[(kk+1)&1][0];
#pragma unroll
        for (int s = 0; s < 4; s++)
          gl_lds16(gsrc + s*4096 + tid*16, nb + s*4096 + w*1024);
      }
      if (kk == 1 && hc < 15) {               // W2 prefetch: after kk0-barrier, so GEMM2(hc-1)
        char* nb = &w2buf[(hc+1)&1][0];       // readers of this buffer are provably done
#pragma unroll
        for (int s = 0; s < 2; s++)
          gl_lds16(w2base + (size_t)(hc+1)*8192 + s*4096 + tid*16, nb + s*4096 + w*1024);
      }
      const char* curw1 = &w1buf[kk&1][0];
#pragma unroll
      for (int ks = 0; ks < 4; ks++)
#pragma unroll
        for (int hf = 0; hf < 4; hf++) {
          // lane-linear conflict-free 16B fragment read
          short8v wf = *(const short8v*)(curw1 + (((ks*4 + hf)*64 + lane) << 4));
          hacc[hf][0] = __builtin_amdgcn_mfma_f32_16x16x32_bf16(wf, xf[0][kk*4+ks], hacc[hf][0], 0,0,0);
          hacc[hf][1] = __builtin_amdgcn_mfma_f32_16x16x32_bf16(wf, xf[1][kk*4+ks], hacc[hf][1], 0,0,0);
        }
      __syncthreads();   // next tile staged + this tile's readers done
    }

    // bias + sigmoid + in-lane bf16 pack: H^T D-frag -> GEMM2 B-frag (no LDS round trip)
    const float* b1p = b1 + t*H_ + hc*64;
    short8v hb[2][2];   // [kb][nf]; elem e=m*4+j holds h = kb*32 + m*16 + g*4 + j
#pragma unroll
    for (int hf = 0; hf < 4; hf++) {
      const int kb = hf >> 1, m = hf & 1;
      f32x4 bv = *(const f32x4*)(b1p + hf*16 + g*4);
#pragma unroll
      for (int nf = 0; nf < 2; nf++)
#pragma unroll
        for (int j = 0; j < 4; j++) {
          float v = hacc[hf][nf][j] + bv[j];
          float s = 1.f / (1.f + __expf(-v));
          hb[kb][nf][m*4 + j] = f2bf(s);
        }
    }

    // GEMM2: O^T += W2^T(scrambled-k) . H^T  (k-permutation cancels between operands)
    const char* curw2 = (hc & 1) ? &w2buf[1][0] : &w2buf[0][0];
#pragma unroll
    for (int kb = 0; kb < 2; kb++)
#pragma unroll
      for (int of = 0; of < 4; of++) {
        short8v wf = *(const short8v*)(curw2 + (((kb*4 + of)*64 + lane) << 4));
        oacc[of][0] = __builtin_amdgcn_mfma_f32_16x16x32_bf16(wf, hb[kb][0], oacc[of][0], 0,0,0);
        oacc[of][1] = __builtin_amdgcn_mfma_f32_16x16x32_bf16(wf, hb[kb][1], oacc[of][1], 0,0,0);
      }
  }

  // epilogue: direct f32x4 stores, no LDS. Lane (r,g) owns 4 consecutive floats per row;
  // 4 lanes (g=0..3) fill each 64B line -> line-granular coalescing.
  const float* b2p = b2 + t*O_;
  float* obase = out + IDX_COUNT + ((size_t)(t*N_ + rblk*128 + w*32))*O_;
#pragma unroll
  for (int nf = 0; nf < 2; nf++)
#pragma unroll
    for (int of = 0; of < 4; of++) {
      f32x4 bv = *(const f32x4*)(b2p + of*16 + g*4);
      f32x4 v;
#pragma unroll
      for (int j = 0; j < 4; j++) v[j] = oacc[of][nf][j] + bv[j];
      *(f32x4*)(obase + (size_t)(nf*16 + r)*O_ + of*16 + g*4) = v;
    }
}

// ---------------- naive f32 fallback (only if ws too small) ----------------
__global__ void naive_kernel(const float* __restrict__ x, const float* __restrict__ W1,
                             const float* __restrict__ b1, const float* __restrict__ W2,
                             const float* __restrict__ b2, float* __restrict__ out) {
  const int row = blockIdx.x;
  const int t = row >> 14;
  __shared__ float xs[512];
  __shared__ float hs[1024];
  const float* xr = x + (size_t)row * D_;
  for (int i = threadIdx.x; i < D_; i += 256) xs[i] = xr[i];
  __syncthreads();
  const float* w1t = W1 + (size_t)t * D_ * H_;
  for (int h = threadIdx.x; h < H_; h += 256) {
    float acc = b1[t*H_ + h];
    for (int k = 0; k < D_; k++) acc += xs[k] * w1t[(size_t)k*H_ + h];
    hs[h] = 1.f / (1.f + __expf(-acc));
  }
  __syncthreads();
  const float* w2t = W2 + (size_t)t * H_ * O_;
  for (int o = threadIdx.x; o < O_; o += 256) {
    float acc = b2[t*O_ + o];
    for (int k = 0; k < H_; k++) acc += hs[k] * w2t[k*O_ + o];
    out[IDX_COUNT + (size_t)row*O_ + o] = acc;
  }
}

extern "C" void kernel_launch(void* const* d_in, const int* in_sizes, int n_in,
                              void* d_out, int out_size, void* d_ws, size_t ws_size,
                              hipStream_t stream) {
  const float* x  = (const float*)d_in[0];
  const float* W1 = (const float*)d_in[1];
  const float* b1 = (const float*)d_in[2];
  const float* W2 = (const float*)d_in[3];
  const float* b2 = (const float*)d_in[4];
  float* out = (float*)d_out;

  idx_kernel<<<IDX_COUNT/256, 256, 0, stream>>>(out);

  const size_t w1_bytes = (size_t)T_*64*16384;   // 8,388,608
  const size_t w2_bytes = (size_t)T_*16*8192;    // 1,048,576
  if (ws_size >= w1_bytes + w2_bytes) {
    char* wsw1 = (char*)d_ws;
    char* wsw2 = wsw1 + w1_bytes;
    prep_w1<<<T_*64, 256, 0, stream>>>(W1, wsw1);
    prep_w2<<<T_*16, 256, 0, stream>>>(W2, wsw2);
    gemm_fused<<<T_*(N_/128), 256, 0, stream>>>(x, b1, b2, wsw1, wsw2, out);
  } else {
    naive_kernel<<<T_*N_, 256, 0, stream>>>(x, W1, b1, W2, b2, out);
  }
}